// Round 4
// baseline (269.442 us; speedup 1.0000x reference)
//
#include <hip/hip_runtime.h>
#include <cstdint>
#include <cstddef>

#define NROWS 262144
#define EMB 256
#define NB 512
#define SLOPE 0.01f

typedef __attribute__((ext_vector_type(8))) short short8;
typedef __attribute__((ext_vector_type(4))) float f32x4;

__device__ __forceinline__ unsigned short f2bf(float f) {
    unsigned u = __float_as_uint(f);
    u += 0x7FFFu + ((u >> 16) & 1u);
    return (unsigned short)(u >> 16);
}

// async 16B global -> LDS (DMA, no VGPR round trip)
__device__ __forceinline__ void gld16(float* l, const float* g) {
    __builtin_amdgcn_global_load_lds(
        (const __attribute__((address_space(1))) unsigned int*)g,
        (__attribute__((address_space(3))) unsigned int*)l, 16, 0, 0);
}

// ---------- prep: transpose W_feat -> bf16 Wt[col][k], zero denom & xg ----------
__global__ __launch_bounds__(256) void k_prep(const float* __restrict__ Wf,
                                              unsigned short* __restrict__ Wt,
                                              float* __restrict__ denom,
                                              float* __restrict__ xg) {
    int b = blockIdx.x, t = threadIdx.x;
    if (b < 256) {
        float v = Wf[(size_t)b * EMB + t];   // W_feat[k=b][col=t]
        Wt[(size_t)t * EMB + b] = f2bf(v);   // Wt[col][k]
        xg[(size_t)b * 512 + t] = 0.f;
        xg[(size_t)b * 512 + 256 + t] = 0.f;
    } else if (b == 256) {
        denom[t] = 0.f;
    } else {
        denom[256 + t] = 0.f;
    }
}

// A-fragment from swizzled LDS tile + gate partial + cvt to bf16
// LDS tile: [64 rows][16 chunks of 16B]; logical chunk c lives at slot c^(row&15)
__device__ __forceinline__ short8 afrag(const float* __restrict__ xb,
                                        const float* __restrict__ wms,
                                        int r, int sub, int fg, int kq, float& gp) {
    const int sl = (sub * 8 + fg * 2) ^ (r & 15);
    const float4 lo = *reinterpret_cast<const float4*>(&xb[r * 64 + sl * 4]);
    const float4 hi = *reinterpret_cast<const float4*>(&xb[r * 64 + (sl ^ 1) * 4]);
    const float4 wa = *reinterpret_cast<const float4*>(&wms[kq]);
    const float4 wb = *reinterpret_cast<const float4*>(&wms[kq + 4]);
    gp += lo.x * wa.x + lo.y * wa.y + lo.z * wa.z + lo.w * wa.w
        + hi.x * wb.x + hi.y * wb.y + hi.z * wb.z + hi.w * wb.w;
    short8 a;
    a[0] = (short)f2bf(lo.x); a[1] = (short)f2bf(lo.y);
    a[2] = (short)f2bf(lo.z); a[3] = (short)f2bf(lo.w);
    a[4] = (short)f2bf(hi.x); a[5] = (short)f2bf(hi.y);
    a[6] = (short)f2bf(hi.z); a[7] = (short)f2bf(hi.w);
    return a;
}

// ---------- fused: gate + exp + bf16 MFMA feat GEMM + weighted segment reduce ----------
// 256 threads (4 waves). Tile 64 rows x 256 cols. A staged via global_load_lds into
// double-buffered 64x64-f32 LDS tiles (2-phase template); B frags from L2 per K-step.
__global__ __launch_bounds__(256, 3) void k_fused(const float* __restrict__ x,
                                                  const unsigned short* __restrict__ Wt,
                                                  const float* __restrict__ wm,
                                                  const float* __restrict__ bfeat,
                                                  const int* __restrict__ bind,
                                                  float* __restrict__ denom,
                                                  float* __restrict__ xg) {
    __shared__ float xbuf[2][64 * 64];   // 2 x 16KB
    __shared__ float wm_s[256];
    __shared__ float w_s[64];
    __shared__ int   seg_s[64];
    __shared__ int   segid_s[4];
    __shared__ int   uni_s[4];

    const int t    = threadIdx.x;
    const int lane = t & 63;
    const int w    = t >> 6;
    const int wr   = w >> 1, wc = w & 1;
    const int fr   = lane & 15;
    const int fg   = lane >> 4;
    const size_t r0 = (size_t)blockIdx.x * 64;

    wm_s[t] = wm[t];
    if (t < 64) seg_s[t] = bind[r0 + t];

    // prologue stage: step 0 -> buf0 (pre-swizzled global source, linear LDS dest)
#pragma unroll
    for (int q = 0; q < 4; q++) {
        const int i = q * 256 + t;
        const int row = i >> 4;
        const int cs  = (i & 15) ^ (row & 15);
        gld16(&xbuf[0][i * 4], x + ((r0 + row) << 8) + (cs << 2));
    }
    __syncthreads();   // wm_s/seg_s visible + buf0 DMA drained

    if (t < 4) {
        int s0 = seg_s[t * 16], ok = 1;
#pragma unroll
        for (int i = 1; i < 16; i++) ok &= (seg_s[t * 16 + i] == s0);
        segid_s[t] = s0;
        uni_s[t]   = ok;
    }

    const unsigned short* wbase = Wt + (size_t)(wc * 128 + fr) * EMB + fg * 8;

    f32x4 acc[2][8];
#pragma unroll
    for (int m = 0; m < 2; m++)
#pragma unroll
        for (int n = 0; n < 8; n++) acc[m][n] = (f32x4){0.f, 0.f, 0.f, 0.f};
    float gp0 = 0.f, gp1 = 0.f;

    // main loop: 4 staging steps of K=64 (2 MFMA substeps each)
#pragma unroll
    for (int s = 0; s < 4; s++) {
        const int cur = s & 1;
        if (s < 3) {   // stage next step into other buffer
#pragma unroll
            for (int q = 0; q < 4; q++) {
                const int i = q * 256 + t;
                const int row = i >> 4;
                const int cs  = (i & 15) ^ (row & 15);
                gld16(&xbuf[cur ^ 1][i * 4],
                      x + ((r0 + row) << 8) + ((s + 1) << 6) + (cs << 2));
            }
        }
        const float* xb = &xbuf[cur][0];
        // B frags for both substeps (L2-resident Wt)
        short8 b0[8], b1[8];
#pragma unroll
        for (int n = 0; n < 8; n++)
            b0[n] = *reinterpret_cast<const short8*>(wbase + n * 16 * EMB + s * 64);
#pragma unroll
        for (int n = 0; n < 8; n++)
            b1[n] = *reinterpret_cast<const short8*>(wbase + n * 16 * EMB + s * 64 + 32);

        // substep 0 (k = s*64 .. +31)
        {
            short8 a0 = afrag(xb, wm_s, wr * 32 + fr,      0, fg, s * 64 + fg * 8, gp0);
            short8 a1 = afrag(xb, wm_s, wr * 32 + 16 + fr, 0, fg, s * 64 + fg * 8, gp1);
#pragma unroll
            for (int n = 0; n < 8; n++) {
                acc[0][n] = __builtin_amdgcn_mfma_f32_16x16x32_bf16(a0, b0[n], acc[0][n], 0, 0, 0);
                acc[1][n] = __builtin_amdgcn_mfma_f32_16x16x32_bf16(a1, b0[n], acc[1][n], 0, 0, 0);
            }
        }
        // substep 1 (k = s*64+32 .. +63)
        {
            short8 a0 = afrag(xb, wm_s, wr * 32 + fr,      1, fg, s * 64 + 32 + fg * 8, gp0);
            short8 a1 = afrag(xb, wm_s, wr * 32 + 16 + fr, 1, fg, s * 64 + 32 + fg * 8, gp1);
#pragma unroll
            for (int n = 0; n < 8; n++) {
                acc[0][n] = __builtin_amdgcn_mfma_f32_16x16x32_bf16(a0, b1[n], acc[0][n], 0, 0, 0);
                acc[1][n] = __builtin_amdgcn_mfma_f32_16x16x32_bf16(a1, b1[n], acc[1][n], 0, 0, 0);
            }
        }
        __syncthreads();   // drain next-stage DMA + release buf[cur] for overwrite
    }

    // ---- gate -> e ----
    gp0 += __shfl_xor(gp0, 16, 64); gp0 += __shfl_xor(gp0, 32, 64);
    gp1 += __shfl_xor(gp1, 16, 64); gp1 += __shfl_xor(gp1, 32, 64);
    // exp(b_mask) cancels in the softmax -> dropped
    if (wc == 0 && lane < 16) {
        w_s[wr * 32 + lane]      = expf(gp0);
        w_s[wr * 32 + 16 + lane] = expf(gp1);
    }
    __syncthreads();

    if (t < 4) {
        if (uni_s[t]) {
            float s = 0.f;
#pragma unroll
            for (int i = 0; i < 16; i++) s += w_s[t * 16 + i];
            atomicAdd(&denom[segid_s[t]], s);
        } else {
            for (int i = 0; i < 16; i++)
                atomicAdd(&denom[seg_s[t * 16 + i]], w_s[t * 16 + i]);
        }
    }

    // ---- epilogue: bias -> leaky -> *e -> segmented reduce -> atomics ----
#pragma unroll
    for (int m = 0; m < 2; m++) {
        const int g    = wr * 2 + m;
        const int uni  = uni_s[g];
        const int sid  = segid_s[g];
        const int rowb = wr * 32 + m * 16;
#pragma unroll
        for (int n = 0; n < 8; n++) {
            const int col = wc * 128 + n * 16 + fr;
            const float bia = bfeat[col];
            float vr[4];
#pragma unroll
            for (int r = 0; r < 4; r++) {
                const int row = rowb + fg * 4 + r;
                float v = acc[m][n][r] + bia;
                v = (v >= 0.f) ? v : SLOPE * v;
                vr[r] = v * w_s[row];
            }
            if (uni) {
                float s = vr[0] + vr[1] + vr[2] + vr[3];
                s += __shfl_xor(s, 16, 64);
                s += __shfl_xor(s, 32, 64);
                if (fg == 0) atomicAdd(&xg[(size_t)sid * EMB + col], s);
            } else {
#pragma unroll
                for (int r = 0; r < 4; r++) {
                    const int row = rowb + fg * 4 + r;
                    atomicAdd(&xg[(size_t)seg_s[row] * EMB + col], vr[r]);
                }
            }
        }
    }
}

// ---------- out = leaky_relu([xg/denom, xg_prev] @ W_t + b_t) + xg_prev ----------
__global__ __launch_bounds__(256) void k_out(const float* __restrict__ xg,
                                             const float* __restrict__ denom,
                                             const float* __restrict__ xgp,
                                             const float* __restrict__ Wtr,
                                             const float* __restrict__ bt,
                                             float* __restrict__ out) {
    __shared__ float h[8][512];
    const int c  = threadIdx.x;
    const int b0 = blockIdx.x * 8;
    float rden[8];
#pragma unroll
    for (int r = 0; r < 8; r++) rden[r] = 1.f / fmaxf(denom[b0 + r], 1e-16f);
#pragma unroll
    for (int q = 0; q < 16; q++) {
        const int r = q >> 1;
        if ((q & 1) == 0) h[r][c]       = xg[(size_t)(b0 + r) * EMB + c] * rden[r];
        else              h[r][EMB + c] = xgp[(size_t)(b0 + r) * EMB + c];
    }
    __syncthreads();
    float acc[8] = {0.f, 0.f, 0.f, 0.f, 0.f, 0.f, 0.f, 0.f};
    for (int k = 0; k < 2 * EMB; k++) {
        float wv = Wtr[(size_t)k * EMB + c];
#pragma unroll
        for (int r = 0; r < 8; r++) acc[r] += h[r][k] * wv;
    }
#pragma unroll
    for (int r = 0; r < 8; r++) {
        float v = acc[r] + bt[c];
        v = (v >= 0.f) ? v : SLOPE * v;
        out[(size_t)(b0 + r) * EMB + c] = v + xgp[(size_t)(b0 + r) * EMB + c];
    }
}

extern "C" void kernel_launch(void* const* d_in, const int* in_sizes, int n_in,
                              void* d_out, int out_size, void* d_ws, size_t ws_size,
                              hipStream_t stream) {
    const float* xgp  = (const float*)d_in[0];
    const float* x    = (const float*)d_in[1];
    const int*   bind = (const int*)d_in[2];
    const float* Wm   = (const float*)d_in[3];
    const float* Wf   = (const float*)d_in[5];
    const float* bf   = (const float*)d_in[6];
    const float* Wtr  = (const float*)d_in[7];
    const float* bt   = (const float*)d_in[8];
    float* out = (float*)d_out;

    char* ws = (char*)d_ws;
    unsigned short* Wt    = (unsigned short*)ws;                  // 256*256 bf16 = 131072 B
    float*          denom = (float*)(ws + 131072);                // 512 f32
    float*          xg    = (float*)(ws + 131072 + 2048);         // 512*256 f32

    hipLaunchKernelGGL(k_prep,  dim3(258),        dim3(256), 0, stream, Wf, Wt, denom, xg);
    hipLaunchKernelGGL(k_fused, dim3(NROWS / 64), dim3(256), 0, stream, x, Wt, Wm, bf, bind, denom, xg);
    hipLaunchKernelGGL(k_out,   dim3(NB / 8),     dim3(256), 0, stream, xg, denom, xgp, Wtr, bt, out);
}